// Round 12
// baseline (168.848 us; speedup 1.0000x reference)
//
#include <hip/hip_runtime.h>
#include <hip/hip_bf16.h>
#include <stdint.h>

static constexpr int M = 4096, N = 4096, K = 4096;
static constexpr float FP8_MAX = 448.0f;

using f32x16 = __attribute__((ext_vector_type(16))) float;
using i32x4  = __attribute__((ext_vector_type(4))) int;
using i32x8  = __attribute__((ext_vector_type(8))) int;

// ---------------- ws layout ----------------
// Aq: [M][K] row-major fp8.
// Bq: fragment-contiguous: [n>>5][k>>6][lane][32B], lane=(n&31)+32*((k>>5)&1)
static constexpr size_t AQ_OFF   = 0;
static constexpr size_t BQ_OFF   = (size_t)M * K;
static constexpr size_t AMAX_OFF = BQ_OFF + (size_t)N * K;

// ---------------- amax reduction ----------------
__global__ __launch_bounds__(256) void amax_kernel(const float* __restrict__ x,
                                                   const float* __restrict__ w,
                                                   float* __restrict__ amax,
                                                   int n4_per_tensor,
                                                   int blocks_per_tensor) {
    const int tensor = blockIdx.x / blocks_per_tensor;
    const int blk    = blockIdx.x % blocks_per_tensor;
    const float4* src = (const float4*)(tensor == 0 ? x : w);

    float m = 0.0f;
    for (int i = blk * blockDim.x + threadIdx.x; i < n4_per_tensor;
         i += blocks_per_tensor * blockDim.x) {
        float4 v = src[i];
        m = fmaxf(m, fmaxf(fmaxf(fabsf(v.x), fabsf(v.y)),
                           fmaxf(fabsf(v.z), fabsf(v.w))));
    }
    #pragma unroll
    for (int off = 32; off >= 1; off >>= 1)
        m = fmaxf(m, __shfl_xor(m, off, 64));

    __shared__ float sm[4];
    const int lane = threadIdx.x & 63, wid = threadIdx.x >> 6;
    if (lane == 0) sm[wid] = m;
    __syncthreads();
    if (threadIdx.x == 0) {
        m = fmaxf(fmaxf(sm[0], sm[1]), fmaxf(sm[2], sm[3]));
        atomicMax((unsigned int*)&amax[tensor], __float_as_uint(m));
    }
}

// ---------------- quantize to fp8 e4m3fn ----------------
// x -> Aq row-major; w -> Bq fragment-contiguous (see ws layout comment).
__global__ __launch_bounds__(256) void quant_kernel(const float* __restrict__ x,
                                                    const float* __restrict__ w,
                                                    unsigned char* __restrict__ aq,
                                                    unsigned char* __restrict__ bq,
                                                    const float* __restrict__ amax,
                                                    int n4_per_tensor) {
    int gid = blockIdx.x * blockDim.x + threadIdx.x;
    const int tensor = (gid >= n4_per_tensor) ? 1 : 0;
    const int i = tensor ? gid - n4_per_tensor : gid;

    const float inv = fmaxf(amax[tensor], 1e-12f) / FP8_MAX;
    const float4* src = (const float4*)(tensor == 0 ? x : w);

    float4 v = src[i];
    float q0 = v.x / inv, q1 = v.y / inv, q2 = v.z / inv, q3 = v.w / inv;
    int packed = __builtin_amdgcn_cvt_pk_fp8_f32(q0, q1, 0, false);
    packed     = __builtin_amdgcn_cvt_pk_fp8_f32(q2, q3, packed, true);

    if (tensor == 0) {
        ((int*)aq)[i] = packed;
    } else {
        const int n  = i >> 10;               // row of w  (1024 float4 per row)
        const int k0 = (i & 1023) * 4;        // first k of this float4
        const int blk = (n >> 5) * (K / 64) + (k0 >> 6);
        const int ln  = (n & 31) + 32 * ((k0 >> 5) & 1);
        ((int*)bq)[blk * 512 + ln * 8 + ((k0 >> 2) & 7)] = packed;
    }
}

// ---------------- fp8 GEMM: single-wave blocks, ZERO barriers --------------
// C[m][n] = sum_k Aq[m][k]*Bq'[n][k];  out = C*scale + bias[n]
// One wave per block; wave tile 128x64 = 4x2 of 32x32 MX mfma 32x32x64 with
// unit E8M0 scales (math == non-scaled fp8).
//
// MECHANISM: every prior round serialized the LDS pipe and matrix pipe
// because s_barrier locked all waves of a block into the same phase
// (measured: tile time == LDS cy + MFMA cy in rounds 4..11).  With 1-wave
// blocks there is NO barrier: 4-5 independent waves/CU self-skew, so one
// wave's MFMA cluster overlaps other waves' ds_reads/DMA (m114 mechanism).
//
// Self-paced correctness (per wave, in-order vm queue):
//   iter t issues: GLOAD_B(t+1) [4 ops] then STAGE_A(t+3) [8 ops]
//   top-of-iter gate vmcnt(8): outstanding = A(t+1)[8],B(t)[4],A(t+2)[8]
//     -> drains A(t+1)+B(t), leaves A(t+2): A(t),A(t+1),B(t) all ready.
//   Slot overwrite safe: reads(t-1) were consumed by MFMA(t-1) (compiler
//   lgkm waits) before iter t issues STAGE into that slot.  Never drains.
static constexpr int BK = 64, DEPTH = 4, NT = K / BK;

__device__ __forceinline__ void gld_lds16(const void* g, void* l) {
    __builtin_amdgcn_global_load_lds(
        (const __attribute__((address_space(1))) void*)g,
        (__attribute__((address_space(3))) void*)l, 16, 0, 0);
}

struct BPair { i32x8 b0, b1; };

__global__ __launch_bounds__(64, 2) void gemm_kernel(const unsigned char* __restrict__ Aq,
                                                     const unsigned char* __restrict__ Bq,
                                                     const float* __restrict__ amax,
                                                     const float* __restrict__ bias,
                                                     float* __restrict__ out) {
    __shared__ unsigned char lds[DEPTH][128 * BK];   // 32 KiB, A ring only

    const int lane = threadIdx.x & 63;

    // XCD-aware swizzle (grid 2048, bijective since 2048 % 8 == 0).
    // XCD k gets swz [k*256, (k+1)*256) = 8 col-panels x all 32 row-tiles
    // -> B panel locality in each XCD's L2 (8 x 256KB = 2MB of Bq).
    const int bid = blockIdx.x;
    const int swz = (bid & 7) * 256 + (bid >> 3);
    const int brow = (swz & 31) * 128;    // 32 row-tiles
    const int bcol = (swz >> 5) * 64;     // 64 col-panels

    const float sx = fmaxf(amax[0], 1e-12f) / FP8_MAX;
    const float sw = fmaxf(amax[1], 1e-12f) / FP8_MAX;
    const float scale = sx * sw;

    // ---- A staging: 8 DMA ops/tile; op o covers rows [o*16, o*16+16) ----
    const int r4  = lane >> 2;                          // row within 16-row seg
    const int chk = ((lane & 3) ^ ((r4 >> 1) & 3)) * 16;  // o*16 even -> swz invariant
    const unsigned char* Abase = Aq + (size_t)brow * K + (size_t)r4 * K + chk;

    // ---- A fragment read offsets (32x32x64: row=lane&31, k=(lane>>5)*32) ----
    const int frow = lane & 31;
    const int swzr = (frow >> 1) & 3;
    const int c0   = (lane >> 5) * 2;
    const int off0 = ((c0 ^ swzr) << 4);
    const int off1 = (((c0 + 1) ^ swzr) << 4);

    // ---- B fragment-direct base pointers (fragment-contiguous layout) ----
    const unsigned char* Bf0 =
        Bq + (size_t)((bcol >> 5) + 0) * (K / 64) * 2048 + (size_t)lane * 32;
    const unsigned char* Bf1 =
        Bq + (size_t)((bcol >> 5) + 1) * (K / 64) * 2048 + (size_t)lane * 32;

    f32x16 acc[4][2] = {};

#define STAGE_A(t, d)                                                          \
    do {                                                                       \
        _Pragma("unroll")                                                      \
        for (int _o = 0; _o < 8; ++_o)                                         \
            gld_lds16(Abase + (size_t)(_o * 16) * K + (size_t)(t) * BK,        \
                      &lds[d][_o * 1024]);                                     \
    } while (0)

#define GLOAD_B(t, BR)                                                         \
    do {                                                                       \
        const size_t _o = (size_t)(t) * 2048;                                  \
        BR.b0 = *(const i32x8*)(Bf0 + _o);                                     \
        BR.b1 = *(const i32x8*)(Bf1 + _o);                                     \
    } while (0)

#define ITER(t, rs, ss, BCUR, BNXT)                                            \
    do {                                                                       \
        asm volatile("s_waitcnt vmcnt(8)" ::: "memory");                       \
        GLOAD_B(((t) + 1 < NT) ? (t) + 1 : NT - 1, BNXT);                      \
        STAGE_A(((t) + 3 < NT) ? (t) + 3 : NT - 1, ss);                        \
        i32x8 _aF[4];                                                          \
        _Pragma("unroll")                                                      \
        for (int _mt = 0; _mt < 4; ++_mt) {                                    \
            const unsigned char* _p = &lds[rs][(_mt * 32 + frow) * BK];        \
            i32x4 _lo = *(const i32x4*)(_p + off0);                            \
            i32x4 _hi = *(const i32x4*)(_p + off1);                            \
            _aF[_mt] = __builtin_shufflevector(_lo, _hi, 0, 1, 2, 3, 4, 5, 6, 7); \
        }                                                                      \
        __builtin_amdgcn_s_setprio(1);                                         \
        _Pragma("unroll")                                                      \
        for (int _mt = 0; _mt < 4; ++_mt) {                                    \
            acc[_mt][0] = __builtin_amdgcn_mfma_scale_f32_32x32x64_f8f6f4(     \
                _aF[_mt], BCUR.b0, acc[_mt][0], 0, 0, 0, 0x7F, 0, 0x7F);       \
            acc[_mt][1] = __builtin_amdgcn_mfma_scale_f32_32x32x64_f8f6f4(     \
                _aF[_mt], BCUR.b1, acc[_mt][1], 0, 0, 0, 0x7F, 0, 0x7F);       \
        }                                                                      \
        __builtin_amdgcn_s_setprio(0);                                         \
    } while (0)

    BPair bP, bQ;

    // prologue (order matters for the gate): A0, B0, A1, A2
    STAGE_A(0, 0);
    GLOAD_B(0, bP);
    STAGE_A(1, 1);
    STAGE_A(2, 2);

    for (int t = 0; t < NT; t += 4) {
        ITER(t + 0, 0, 3, bP, bQ);
        ITER(t + 1, 1, 0, bQ, bP);
        ITER(t + 2, 2, 1, bP, bQ);
        ITER(t + 3, 3, 2, bQ, bP);
    }
#undef ITER
#undef GLOAD_B
#undef STAGE_A

    // epilogue.  32x32 C/D: col=lane&31, row=(reg&3)+8*(reg>>2)+4*(lane>>5)
    #pragma unroll
    for (int mt = 0; mt < 4; ++mt) {
        const int rbase = brow + mt * 32 + 4 * (lane >> 5);
        #pragma unroll
        for (int nt2 = 0; nt2 < 2; ++nt2) {
            const int col = bcol + nt2 * 32 + (lane & 31);
            const float b = bias[col];
            #pragma unroll
            for (int reg = 0; reg < 16; ++reg) {
                const int row = rbase + (reg & 3) + 8 * (reg >> 2);
                out[(size_t)row * N + col] = acc[mt][nt2][reg] * scale + b;
            }
        }
    }
}

extern "C" void kernel_launch(void* const* d_in, const int* in_sizes, int n_in,
                              void* d_out, int out_size, void* d_ws, size_t ws_size,
                              hipStream_t stream) {
    const float* x    = (const float*)d_in[0];   // [4,1024,4096] f32 -> [4096][4096]
    const float* w    = (const float*)d_in[1];   // [4096][4096] f32
    const float* bias = (const float*)d_in[2];   // [4096] f32
    float* out = (float*)d_out;

    unsigned char* aq = (unsigned char*)d_ws + AQ_OFF;
    unsigned char* bq = (unsigned char*)d_ws + BQ_OFF;
    float* amax = (float*)((unsigned char*)d_ws + AMAX_OFF);

    const int n4 = (M * K) / 4;

    hipMemsetAsync(amax, 0, 2 * sizeof(float), stream);  // capturable async memset

    const int blocks_per_tensor = 512;
    amax_kernel<<<2 * blocks_per_tensor, 256, 0, stream>>>(x, w, amax, n4, blocks_per_tensor);

    const int quant_blocks = (2 * n4) / 256;
    quant_kernel<<<quant_blocks, 256, 0, stream>>>(x, w, aq, bq, amax, n4);

    gemm_kernel<<<2048, 64, 0, stream>>>(aq, bq, amax, bias, out);
}

// Round 13
// 164.212 us; speedup vs baseline: 1.0282x; 1.0282x over previous
//
#include <hip/hip_runtime.h>
#include <hip/hip_bf16.h>
#include <stdint.h>

static constexpr int M = 4096, N = 4096, K = 4096;
static constexpr float FP8_MAX = 448.0f;

using f32x16 = __attribute__((ext_vector_type(16))) float;
using i32x4  = __attribute__((ext_vector_type(4))) int;
using i32x8  = __attribute__((ext_vector_type(8))) int;

// ---------------- ws layout ----------------
// Aq AND Bq in MFMA-fragment-contiguous layout:
//   [row>>5][k>>6][lane][32B],  lane = (row&31) + 32*((k>>5)&1)
// so one 32-row x 64-k fragment = 2048 contiguous bytes = one wave-coalesced
// load (row=lane&31, k=(lane>>5)*32 — exactly the 32x32x64 operand mapping).
static constexpr size_t AQ_OFF   = 0;
static constexpr size_t BQ_OFF   = (size_t)M * K;
static constexpr size_t AMAX_OFF = BQ_OFF + (size_t)N * K;

// ---------------- amax reduction ----------------
__global__ __launch_bounds__(256) void amax_kernel(const float* __restrict__ x,
                                                   const float* __restrict__ w,
                                                   float* __restrict__ amax,
                                                   int n4_per_tensor,
                                                   int blocks_per_tensor) {
    const int tensor = blockIdx.x / blocks_per_tensor;
    const int blk    = blockIdx.x % blocks_per_tensor;
    const float4* src = (const float4*)(tensor == 0 ? x : w);

    float m = 0.0f;
    for (int i = blk * blockDim.x + threadIdx.x; i < n4_per_tensor;
         i += blocks_per_tensor * blockDim.x) {
        float4 v = src[i];
        m = fmaxf(m, fmaxf(fmaxf(fabsf(v.x), fabsf(v.y)),
                           fmaxf(fabsf(v.z), fabsf(v.w))));
    }
    #pragma unroll
    for (int off = 32; off >= 1; off >>= 1)
        m = fmaxf(m, __shfl_xor(m, off, 64));

    __shared__ float sm[4];
    const int lane = threadIdx.x & 63, wid = threadIdx.x >> 6;
    if (lane == 0) sm[wid] = m;
    __syncthreads();
    if (threadIdx.x == 0) {
        m = fmaxf(fmaxf(sm[0], sm[1]), fmaxf(sm[2], sm[3]));
        atomicMax((unsigned int*)&amax[tensor], __float_as_uint(m));
    }
}

// ---------------- quantize to fp8 e4m3fn, fragment-contiguous output -------
__global__ __launch_bounds__(256) void quant_kernel(const float* __restrict__ x,
                                                    const float* __restrict__ w,
                                                    unsigned char* __restrict__ aq,
                                                    unsigned char* __restrict__ bq,
                                                    const float* __restrict__ amax,
                                                    int n4_per_tensor) {
    int gid = blockIdx.x * blockDim.x + threadIdx.x;
    const int tensor = (gid >= n4_per_tensor) ? 1 : 0;
    const int i = tensor ? gid - n4_per_tensor : gid;

    const float inv = fmaxf(amax[tensor], 1e-12f) / FP8_MAX;
    const float4* src = (const float4*)(tensor == 0 ? x : w);
    int* dst = (int*)(tensor == 0 ? aq : bq);

    float4 v = src[i];
    float q0 = v.x / inv, q1 = v.y / inv, q2 = v.z / inv, q3 = v.w / inv;
    int packed = __builtin_amdgcn_cvt_pk_fp8_f32(q0, q1, 0, false);
    packed     = __builtin_amdgcn_cvt_pk_fp8_f32(q2, q3, packed, true);

    // element [r][k0..k0+3] -> fragment-contiguous position
    const int r  = i >> 10;               // row (1024 float4 per row, K=4096)
    const int k0 = (i & 1023) * 4;        // first k of this float4
    const int blk = (r >> 5) * (K / 64) + (k0 >> 6);
    const int ln  = (r & 31) + 32 * ((k0 >> 5) & 1);
    dst[blk * 512 + ln * 8 + ((k0 >> 2) & 7)] = packed;
}

// ---------------- fp8 GEMM: ZERO-LDS, fragment-direct, register pipeline ---
// C[m][n] = sum_k Aq'[m][k]*Bq'[n][k];  out = C*scale + bias[n]
// 8 waves (2M x 4N), wave tile 64x64 = 2x2 of 32x32 MX mfma 32x32x64 with
// unit E8M0 scales (math == non-scaled fp8).
//
// MECHANISM: 9 scheduling variants showed tile time ~= LDS cy + MFMA cy
// whenever operands flow through LDS; MX-fp8 needs ~238 B/cy/CU vs LDS ~85.
// Here NO LDS, NO barriers, NO ds_read: each operand fragment is a single
// contiguous 2KB wave-coalesced global load (Aq/Bq pre-swizzled by quant).
// 2-deep register ping-pong (sets S0/S1); loads are plain C++ loads so the
// compiler emits exact counted vmcnt before each MFMA use; per-iter order
// {MFMA(t); reload set with t+2; sched_barrier} = ~2-iter lookahead, and
// Aq+Bq (32MB) is L3-resident (written by quant just before).
// The 4 waves sharing wr load IDENTICAL A addresses -> L1 broadcast.
static constexpr int BK = 64, NT = K / BK;

struct FragSet { i32x8 a0, a1, b0, b1; };   // 32 VGPR

__global__ __launch_bounds__(512, 2) void gemm_kernel(const unsigned char* __restrict__ Aq,
                                                      const unsigned char* __restrict__ Bq,
                                                      const float* __restrict__ amax,
                                                      const float* __restrict__ bias,
                                                      float* __restrict__ out) {
    const int tid  = threadIdx.x;
    const int lane = tid & 63;
    const int w    = tid >> 6;            // 0..7
    const int wr   = w >> 2, wc = w & 3;  // 2M x 4N waves, 64x64 each

    // XCD-aware swizzle (grid 512, bijective since 512 % 8 == 0)
    const int bid = blockIdx.x;
    const int swz = (bid & 7) * 64 + (bid >> 3);
    const int brow = (swz >> 4) * 128;    // 32 row-tiles  (block tile 128x256)
    const int bcol = (swz & 15) * 256;    // 16 col-tiles

    const float sx = fmaxf(amax[0], 1e-12f) / FP8_MAX;
    const float sw = fmaxf(amax[1], 1e-12f) / FP8_MAX;
    const float scale = sx * sw;

    // ---- fragment-direct base pointers ----
    const size_t KB = (size_t)(K / 64) * 2048;    // bytes per 32-row panel
    const unsigned char* Af0 = Aq + (size_t)((brow >> 5) + wr * 2 + 0) * KB + (size_t)lane * 32;
    const unsigned char* Af1 = Aq + (size_t)((brow >> 5) + wr * 2 + 1) * KB + (size_t)lane * 32;
    const unsigned char* Bf0 = Bq + (size_t)((bcol >> 5) + wc * 2 + 0) * KB + (size_t)lane * 32;
    const unsigned char* Bf1 = Bq + (size_t)((bcol >> 5) + wc * 2 + 1) * KB + (size_t)lane * 32;

    f32x16 acc[2][2] = {};

#define LOADF(t, S)                                                            \
    do {                                                                       \
        const size_t _o = (size_t)(t) * 2048;                                  \
        S.a0 = *(const i32x8*)(Af0 + _o);                                      \
        S.a1 = *(const i32x8*)(Af1 + _o);                                      \
        S.b0 = *(const i32x8*)(Bf0 + _o);                                      \
        S.b1 = *(const i32x8*)(Bf1 + _o);                                      \
    } while (0)

#define MX(a, b, c) \
    __builtin_amdgcn_mfma_scale_f32_32x32x64_f8f6f4((a), (b), (c), 0, 0, 0, 0x7F, 0, 0x7F)

#define ITER(t, S)                                                             \
    do {                                                                       \
        __builtin_amdgcn_s_setprio(1);                                         \
        acc[0][0] = MX(S.a0, S.b0, acc[0][0]);                                 \
        acc[0][1] = MX(S.a0, S.b1, acc[0][1]);                                 \
        acc[1][0] = MX(S.a1, S.b0, acc[1][0]);                                 \
        acc[1][1] = MX(S.a1, S.b1, acc[1][1]);                                 \
        __builtin_amdgcn_s_setprio(0);                                         \
        LOADF(((t) + 2 < NT) ? (t) + 2 : NT - 1, S);                           \
        __builtin_amdgcn_sched_barrier(0);                                     \
    } while (0)

    FragSet s0, s1;
    LOADF(0, s0);
    LOADF(1, s1);

    for (int t = 0; t < NT; t += 2) {
        ITER(t + 0, s0);
        ITER(t + 1, s1);
    }
#undef ITER
#undef MX
#undef LOADF

    // epilogue.  32x32 C/D: col=lane&31, row=(reg&3)+8*(reg>>2)+4*(lane>>5)
    #pragma unroll
    for (int mt = 0; mt < 2; ++mt) {
        const int rbase = brow + wr * 64 + mt * 32 + 4 * (lane >> 5);
        #pragma unroll
        for (int nt2 = 0; nt2 < 2; ++nt2) {
            const int col = bcol + wc * 64 + nt2 * 32 + (lane & 31);
            const float b = bias[col];
            #pragma unroll
            for (int reg = 0; reg < 16; ++reg) {
                const int row = rbase + (reg & 3) + 8 * (reg >> 2);
                out[(size_t)row * N + col] = acc[mt][nt2][reg] * scale + b;
            }
        }
    }
}

extern "C" void kernel_launch(void* const* d_in, const int* in_sizes, int n_in,
                              void* d_out, int out_size, void* d_ws, size_t ws_size,
                              hipStream_t stream) {
    const float* x    = (const float*)d_in[0];   // [4,1024,4096] f32 -> [4096][4096]
    const float* w    = (const float*)d_in[1];   // [4096][4096] f32
    const float* bias = (const float*)d_in[2];   // [4096] f32
    float* out = (float*)d_out;

    unsigned char* aq = (unsigned char*)d_ws + AQ_OFF;
    unsigned char* bq = (unsigned char*)d_ws + BQ_OFF;
    float* amax = (float*)((unsigned char*)d_ws + AMAX_OFF);

    const int n4 = (M * K) / 4;

    hipMemsetAsync(amax, 0, 2 * sizeof(float), stream);  // capturable async memset

    const int blocks_per_tensor = 512;
    amax_kernel<<<2 * blocks_per_tensor, 256, 0, stream>>>(x, w, amax, n4, blocks_per_tensor);

    const int quant_blocks = (2 * n4) / 256;
    quant_kernel<<<quant_blocks, 256, 0, stream>>>(x, w, aq, bq, amax, n4);

    gemm_kernel<<<512, 512, 0, stream>>>(aq, bq, amax, bias, out);
}

// Round 14
// 132.023 us; speedup vs baseline: 1.2789x; 1.2438x over previous
//
#include <hip/hip_runtime.h>
#include <hip/hip_bf16.h>
#include <stdint.h>

static constexpr int M = 4096, N = 4096, K = 4096;
static constexpr float FP8_MAX = 448.0f;

using f32x16 = __attribute__((ext_vector_type(16))) float;
using i32x4  = __attribute__((ext_vector_type(4))) int;
using i32x8  = __attribute__((ext_vector_type(8))) int;

// ---------------- ws layout ----------------
static constexpr size_t AQ_OFF   = 0;
static constexpr size_t BQ_OFF   = (size_t)M * K;
static constexpr size_t AMAX_OFF = BQ_OFF + (size_t)N * K;

// ---------------- amax reduction ----------------
__global__ __launch_bounds__(256) void amax_kernel(const float* __restrict__ x,
                                                   const float* __restrict__ w,
                                                   float* __restrict__ amax,
                                                   int n4_per_tensor,
                                                   int blocks_per_tensor) {
    const int tensor = blockIdx.x / blocks_per_tensor;
    const int blk    = blockIdx.x % blocks_per_tensor;
    const float4* src = (const float4*)(tensor == 0 ? x : w);

    float m = 0.0f;
    for (int i = blk * blockDim.x + threadIdx.x; i < n4_per_tensor;
         i += blocks_per_tensor * blockDim.x) {
        float4 v = src[i];
        m = fmaxf(m, fmaxf(fmaxf(fabsf(v.x), fabsf(v.y)),
                           fmaxf(fabsf(v.z), fabsf(v.w))));
    }
    #pragma unroll
    for (int off = 32; off >= 1; off >>= 1)
        m = fmaxf(m, __shfl_xor(m, off, 64));

    __shared__ float sm[4];
    const int lane = threadIdx.x & 63, wid = threadIdx.x >> 6;
    if (lane == 0) sm[wid] = m;
    __syncthreads();
    if (threadIdx.x == 0) {
        m = fmaxf(fmaxf(sm[0], sm[1]), fmaxf(sm[2], sm[3]));
        atomicMax((unsigned int*)&amax[tensor], __float_as_uint(m));
    }
}

// ---------------- quantize to fp8 e4m3fn (8 floats / thread) ----------------
__global__ __launch_bounds__(256) void quant_kernel(const float* __restrict__ x,
                                                    const float* __restrict__ w,
                                                    unsigned char* __restrict__ aq,
                                                    unsigned char* __restrict__ bq,
                                                    const float* __restrict__ amax,
                                                    int n8_per_tensor) {
    int gid = blockIdx.x * blockDim.x + threadIdx.x;
    const int tensor = (gid >= n8_per_tensor) ? 1 : 0;
    const int i = tensor ? gid - n8_per_tensor : gid;   // 8-float unit index

    const float inv = fmaxf(amax[tensor], 1e-12f) / FP8_MAX;
    const float4* src = (const float4*)(tensor == 0 ? x : w);
    int2* dst = (int2*)(tensor == 0 ? aq : bq);

    float4 v0 = src[i * 2 + 0];
    float4 v1 = src[i * 2 + 1];
    // IEEE division to bitwise-match the reference's x / inv_scale
    int p0 = __builtin_amdgcn_cvt_pk_fp8_f32(v0.x / inv, v0.y / inv, 0, false);
    p0     = __builtin_amdgcn_cvt_pk_fp8_f32(v0.z / inv, v0.w / inv, p0, true);
    int p1 = __builtin_amdgcn_cvt_pk_fp8_f32(v1.x / inv, v1.y / inv, 0, false);
    p1     = __builtin_amdgcn_cvt_pk_fp8_f32(v1.z / inv, v1.w / inv, p1, true);
    dst[i] = make_int2(p0, p1);
}

// ---------------- fp8 GEMM: 256^2, DEPTH-4 ring, 2-phase double-barrier ----
// (round-7 configuration — best measured: 74.4 us, 1847 TF MX-fp8)
// C[m][n] = sum_k Aq[m][k]*Bq[n][k];  out = C*scale + bias[n]
// 8 waves (2M x 4N), each 128x64 via 4x2 of 32x32; MX mfma 32x32x64, unit
// E8M0 scales (math == non-scaled fp8).
static constexpr int BM = 256, BN = 256, BK = 64, DEPTH = 4, NT = K / BK;

__device__ __forceinline__ void gld_lds16(const void* g, void* l) {
    __builtin_amdgcn_global_load_lds(
        (const __attribute__((address_space(1))) void*)g,
        (__attribute__((address_space(3))) void*)l, 16, 0, 0);
}

__global__ __launch_bounds__(512, 2) void gemm_kernel(const unsigned char* __restrict__ Aq,
                                                      const unsigned char* __restrict__ Bq,
                                                      const float* __restrict__ amax,
                                                      const float* __restrict__ bias,
                                                      float* __restrict__ out) {
    __shared__ unsigned char lds[DEPTH][2][BM * BK];   // 128 KiB

    const int tid  = threadIdx.x;
    const int lane = tid & 63;
    const int w    = tid >> 6;            // 0..7
    const int wr   = w >> 2, wc = w & 3;  // 2M x 4N waves, 128x64 each

    // XCD-aware swizzle (grid 256, bijective since 256 % 8 == 0)
    const int bid = blockIdx.x;
    const int swz = (bid & 7) * 32 + (bid >> 3);
    const int brow = (swz >> 4) * BM;
    const int bcol = (swz & 15) * BN;

    const float sx = fmaxf(amax[0], 1e-12f) / FP8_MAX;
    const float sw = fmaxf(amax[1], 1e-12f) / FP8_MAX;
    const float scale = sx * sw;

    // ---- staging addresses (pre-swizzled global chunk, linear LDS dest) ----
    const int r4    = lane >> 2;
    const int row0  = w * 16 + r4;
    const int chk   = ((lane & 3) ^ ((row0 >> 1) & 3)) * 16;
    const unsigned char* Abase = Aq + (size_t)brow * K;
    const unsigned char* Bbase = Bq + (size_t)bcol * K;

    // ---- fragment read offsets (32x32x64: row=lane&31, k=(lane>>5)*32) ----
    const int frow = lane & 31;
    const int swzr = (frow >> 1) & 3;
    const int c0   = (lane >> 5) * 2;
    const int off0 = ((c0 ^ swzr) << 4);
    const int off1 = (((c0 + 1) ^ swzr) << 4);

    f32x16 acc[4][2] = {};

#define STAGE(t, d)                                                                            \
    do {                                                                                       \
        const size_t _k0 = (size_t)(t) * BK;                                                   \
        gld_lds16(Abase + (size_t)row0 * K + _k0 + chk,         &lds[d][0][w * 1024]);         \
        gld_lds16(Abase + (size_t)(row0 + 128) * K + _k0 + chk, &lds[d][0][8192 + w * 1024]);  \
        gld_lds16(Bbase + (size_t)row0 * K + _k0 + chk,         &lds[d][1][w * 1024]);         \
        gld_lds16(Bbase + (size_t)(row0 + 128) * K + _k0 + chk, &lds[d][1][8192 + w * 1024]);  \
    } while (0)

#define READ_FRAG(F, base_row, rs, ab)                                         \
    do {                                                                       \
        const unsigned char* _p = &lds[rs][ab][((base_row) + frow) * BK];      \
        i32x4 _lo = *(const i32x4*)(_p + off0);                                \
        i32x4 _hi = *(const i32x4*)(_p + off1);                                \
        F = __builtin_shufflevector(_lo, _hi, 0, 1, 2, 3, 4, 5, 6, 7);         \
    } while (0)

#define MXMFMA(a, b, c) \
    __builtin_amdgcn_mfma_scale_f32_32x32x64_f8f6f4((a), (b), (c), 0, 0, 0, 0x7F, 0, 0x7F)

#define ITER(t, rs, ss)                                                        \
    do {                                                                       \
        i32x8 _b0, _b1, _a0, _a1, _a2, _a3;                                    \
        /* ---- phase 1: issue ---- */                                         \
        READ_FRAG(_b0, wc * 64 +  0, rs, 1);                                   \
        READ_FRAG(_b1, wc * 64 + 32, rs, 1);                                   \
        READ_FRAG(_a0, wr * 128 +  0, rs, 0);                                  \
        READ_FRAG(_a1, wr * 128 + 32, rs, 0);                                  \
        STAGE(((t) + 3 < NT) ? (t) + 3 : NT - 1, ss);                          \
        __builtin_amdgcn_s_barrier();                                          \
        asm volatile("s_waitcnt lgkmcnt(0)" ::: "memory");                     \
        __builtin_amdgcn_s_setprio(1);                                         \
        acc[0][0] = MXMFMA(_a0, _b0, acc[0][0]);                               \
        acc[0][1] = MXMFMA(_a0, _b1, acc[0][1]);                               \
        acc[1][0] = MXMFMA(_a1, _b0, acc[1][0]);                               \
        acc[1][1] = MXMFMA(_a1, _b1, acc[1][1]);                               \
        __builtin_amdgcn_s_setprio(0);                                         \
        __builtin_amdgcn_s_barrier();                                          \
        /* ---- phase 2: issue ---- */                                         \
        READ_FRAG(_a2, wr * 128 + 64, rs, 0);                                  \
        READ_FRAG(_a3, wr * 128 + 96, rs, 0);                                  \
        __builtin_amdgcn_s_barrier();                                          \
        asm volatile("s_waitcnt lgkmcnt(0)" ::: "memory");                     \
        __builtin_amdgcn_s_setprio(1);                                         \
        acc[2][0] = MXMFMA(_a2, _b0, acc[2][0]);                               \
        acc[2][1] = MXMFMA(_a2, _b1, acc[2][1]);                               \
        acc[3][0] = MXMFMA(_a3, _b0, acc[3][0]);                               \
        acc[3][1] = MXMFMA(_a3, _b1, acc[3][1]);                               \
        __builtin_amdgcn_s_setprio(0);                                         \
        asm volatile("s_waitcnt vmcnt(8)" ::: "memory");                       \
        __builtin_amdgcn_s_barrier();                                          \
    } while (0)

    // prologue: tiles 0,1,2 -> slots 0,1,2; gate tile 0 for all waves
    STAGE(0, 0);
    STAGE(1, 1);
    STAGE(2, 2);
    asm volatile("s_waitcnt vmcnt(8)" ::: "memory");   // tile 0 landed (this wave)
    __builtin_amdgcn_s_barrier();                      // ... for all waves

    for (int t = 0; t < NT; t += 4) {
        ITER(t + 0, 0, 3);
        ITER(t + 1, 1, 0);
        ITER(t + 2, 2, 1);
        ITER(t + 3, 3, 2);
    }
#undef ITER
#undef MXMFMA
#undef READ_FRAG
#undef STAGE

    // epilogue.  32x32 C/D: col=lane&31, row=(reg&3)+8*(reg>>2)+4*(lane>>5)
    #pragma unroll
    for (int mt = 0; mt < 4; ++mt) {
        const int rbase = brow + wr * 128 + mt * 32 + 4 * (lane >> 5);
        #pragma unroll
        for (int nt2 = 0; nt2 < 2; ++nt2) {
            const int col = bcol + wc * 64 + nt2 * 32 + (lane & 31);
            const float b = bias[col];
            #pragma unroll
            for (int reg = 0; reg < 16; ++reg) {
                const int row = rbase + (reg & 3) + 8 * (reg >> 2);
                out[(size_t)row * N + col] = acc[mt][nt2][reg] * scale + b;
            }
        }
    }
}

extern "C" void kernel_launch(void* const* d_in, const int* in_sizes, int n_in,
                              void* d_out, int out_size, void* d_ws, size_t ws_size,
                              hipStream_t stream) {
    const float* x    = (const float*)d_in[0];   // [4,1024,4096] f32 -> [4096][4096]
    const float* w    = (const float*)d_in[1];   // [4096][4096] f32
    const float* bias = (const float*)d_in[2];   // [4096] f32
    float* out = (float*)d_out;

    unsigned char* aq = (unsigned char*)d_ws + AQ_OFF;
    unsigned char* bq = (unsigned char*)d_ws + BQ_OFF;
    float* amax = (float*)((unsigned char*)d_ws + AMAX_OFF);

    hipMemsetAsync(amax, 0, 2 * sizeof(float), stream);  // capturable async memset

    const int n4 = (M * K) / 4;
    const int blocks_per_tensor = 512;
    amax_kernel<<<2 * blocks_per_tensor, 256, 0, stream>>>(x, w, amax, n4, blocks_per_tensor);

    const int n8 = (M * K) / 8;                  // 8 floats per thread
    const int quant_blocks = (2 * n8) / 256;     // 16384 blocks
    quant_kernel<<<quant_blocks, 256, 0, stream>>>(x, w, aq, bq, amax, n8);

    dim3 grid(256);
    gemm_kernel<<<grid, 512, 0, stream>>>(aq, bq, amax, bias, out);
}